// Round 4
// baseline (175.383 us; speedup 1.0000x reference)
//
#include <hip/hip_runtime.h>
#include <hip/hip_bf16.h>
#include <cmath>

#define T_DIM 1024
#define B_DIM 8
#define C_DIM 256
#define H_DIM 8
#define D_DIM 32
#define F_DIM 512

typedef __attribute__((ext_vector_type(4))) float f32x4;
typedef __attribute__((ext_vector_type(8))) short bf16x8;

static __device__ __forceinline__ unsigned short f2bf(float f) {
    union { float f; unsigned u; } v; v.f = f;
    unsigned r = v.u + 0x7fff + ((v.u >> 16) & 1);
    return (unsigned short)(r >> 16);
}
static __device__ __forceinline__ float bf2f(unsigned short h) {
    union { unsigned u; float f; } v; v.u = ((unsigned)h) << 16;
    return v.f;
}

// async global->LDS, 16B per lane; LDS dest = wave-uniform base + lane*16
static __device__ __forceinline__ void gload_lds16(const void* g, void* l) {
    __builtin_amdgcn_global_load_lds(
        (const __attribute__((address_space(1))) unsigned int*)g,
        (__attribute__((address_space(3))) unsigned int*)l,
        16, 0, 0);
}

// ---------------------------------------------------------------------------
// Convert the 4 weight matrices f32 -> bf16 into one contiguous ws region.
// ---------------------------------------------------------------------------
__global__ __launch_bounds__(256) void convert_weights(const float* __restrict__ wqkv,
                                                       const float* __restrict__ wo,
                                                       const float* __restrict__ w1,
                                                       const float* __restrict__ w2,
                                                       unsigned short* __restrict__ dst)
{
    int e = blockIdx.x * 256 + threadIdx.x;
    const float* src; int off;
    if (e < 196608)      { src = wqkv; off = 0; }
    else if (e < 262144) { src = wo;   off = 196608; }
    else if (e < 393216) { src = w1;   off = 262144; }
    else                 { src = w2;   off = 393216; }
    dst[e] = f2bf(src[e - off]);
}

// ---------------------------------------------------------------------------
// LayerNorm, f32 input: one wave per row of C=256, float4 per lane, bf16 out.
// ---------------------------------------------------------------------------
__global__ __launch_bounds__(256) void ln_bf16(const float* __restrict__ x,
                                               const float* __restrict__ g,
                                               const float* __restrict__ bta,
                                               unsigned short* __restrict__ y)
{
    int row  = blockIdx.x * 4 + (threadIdx.x >> 6);
    int lane = threadIdx.x & 63;
    float4 v = ((const float4*)(x + (size_t)row * C_DIM))[lane];
    float s  = v.x + v.y + v.z + v.w;
    float ss = v.x * v.x + v.y * v.y + v.z * v.z + v.w * v.w;
#pragma unroll
    for (int off = 1; off < 64; off <<= 1) {
        s  += __shfl_xor(s, off);
        ss += __shfl_xor(ss, off);
    }
    float mu   = s * (1.0f / C_DIM);
    float var  = ss * (1.0f / C_DIM) - mu * mu;
    float rstd = rsqrtf(var + 1e-5f);
    float4 gv = ((const float4*)g)[lane];
    float4 bv = ((const float4*)bta)[lane];
    ushort4 o;
    o.x = f2bf((v.x - mu) * rstd * gv.x + bv.x);
    o.y = f2bf((v.y - mu) * rstd * gv.y + bv.y);
    o.z = f2bf((v.z - mu) * rstd * gv.z + bv.z);
    o.w = f2bf((v.w - mu) * rstd * gv.w + bv.w);
    ((ushort4*)(y + (size_t)row * C_DIM))[lane] = o;
}

// LayerNorm, bf16 input variant.
__global__ __launch_bounds__(256) void ln_bf16i(const unsigned short* __restrict__ x,
                                                const float* __restrict__ g,
                                                const float* __restrict__ bta,
                                                unsigned short* __restrict__ y)
{
    int row  = blockIdx.x * 4 + (threadIdx.x >> 6);
    int lane = threadIdx.x & 63;
    ushort4 hv = ((const ushort4*)(x + (size_t)row * C_DIM))[lane];
    float4 v = {bf2f(hv.x), bf2f(hv.y), bf2f(hv.z), bf2f(hv.w)};
    float s  = v.x + v.y + v.z + v.w;
    float ss = v.x * v.x + v.y * v.y + v.z * v.z + v.w * v.w;
#pragma unroll
    for (int off = 1; off < 64; off <<= 1) {
        s  += __shfl_xor(s, off);
        ss += __shfl_xor(ss, off);
    }
    float mu   = s * (1.0f / C_DIM);
    float var  = ss * (1.0f / C_DIM) - mu * mu;
    float rstd = rsqrtf(var + 1e-5f);
    float4 gv = ((const float4*)g)[lane];
    float4 bv = ((const float4*)bta)[lane];
    ushort4 o;
    o.x = f2bf((v.x - mu) * rstd * gv.x + bv.x);
    o.y = f2bf((v.y - mu) * rstd * gv.y + bv.y);
    o.z = f2bf((v.z - mu) * rstd * gv.z + bv.z);
    o.w = f2bf((v.w - mu) * rstd * gv.w + bv.w);
    ((ushort4*)(y + (size_t)row * C_DIM))[lane] = o;
}

// ---------------------------------------------------------------------------
// bf16 MFMA GEMM: out[m,n] = A[m,k] * W[n,k] + bias[n]
// BM=128, BN=64, BK=64, 4 waves. global_load_lds(16B), source-swizzled LDS.
// EPI: 0 store bf16 | 1 GELU->bf16 | 2 +R(f32)->bf16 | 3 +R(bf16)->f32
// ---------------------------------------------------------------------------
template<int EPI>
__global__ __launch_bounds__(256) void gemm_mfma(const unsigned short* __restrict__ A,
                                                 const unsigned short* __restrict__ W,
                                                 const float* __restrict__ bias,
                                                 const void* __restrict__ Rv,
                                                 void* __restrict__ outv,
                                                 int N, int K)
{
    __shared__ __align__(16) unsigned short A_s[128 * 64];
    __shared__ __align__(16) unsigned short W_s[64 * 64];
    int tid  = threadIdx.x;
    int lane = tid & 63;
    int wv   = tid >> 6;
    int l15  = lane & 15, lg = lane >> 4;
    int row0 = blockIdx.y * 128;
    int col0 = blockIdx.x * 64;

    f32x4 acc[2][4] = {};
    for (int k0 = 0; k0 < K; k0 += 64) {
#pragma unroll
        for (int i = 0; i < 4; i++) {                 // A tile: 128x64 bf16
            int u = (wv * 4 + i) * 64 + lane;
            int r = u >> 3, c = u & 7;
            gload_lds16(A + (size_t)(row0 + r) * K + k0 + ((c ^ (r & 7)) * 8),
                        &A_s[(size_t)(wv * 4 + i) * 512]);
        }
#pragma unroll
        for (int j = 0; j < 2; j++) {                 // W tile: 64x64 bf16
            int u = (wv * 2 + j) * 64 + lane;
            int r = u >> 3, c = u & 7;
            gload_lds16(W + (size_t)(col0 + r) * K + k0 + ((c ^ (r & 7)) * 8),
                        &W_s[(size_t)(wv * 2 + j) * 512]);
        }
        __syncthreads();
#pragma unroll
        for (int kk = 0; kk < 2; kk++) {
            bf16x8 af[2], wf[4];
#pragma unroll
            for (int mb = 0; mb < 2; mb++) {
                int rowa = wv * 32 + mb * 16 + l15;
                af[mb] = *(const bf16x8*)&A_s[rowa * 64 + (((kk * 4 + lg) ^ (l15 & 7)) * 8)];
            }
#pragma unroll
            for (int nb = 0; nb < 4; nb++) {
                int roww = nb * 16 + l15;
                wf[nb] = *(const bf16x8*)&W_s[roww * 64 + (((kk * 4 + lg) ^ (l15 & 7)) * 8)];
            }
#pragma unroll
            for (int mb = 0; mb < 2; mb++)
#pragma unroll
                for (int nb = 0; nb < 4; nb++)
                    acc[mb][nb] = __builtin_amdgcn_mfma_f32_16x16x32_bf16(af[mb], wf[nb], acc[mb][nb], 0, 0, 0);
        }
        __syncthreads();
    }
#pragma unroll
    for (int nb = 0; nb < 4; nb++) {
        int c = col0 + nb * 16 + l15;
        float bv = bias[c];
#pragma unroll
        for (int mb = 0; mb < 2; mb++) {
#pragma unroll
            for (int r = 0; r < 4; r++) {
                int rowm = row0 + wv * 32 + mb * 16 + lg * 4 + r;
                float v = acc[mb][nb][r] + bv;
                if (EPI == 1) v = 0.5f * v * (1.0f + erff(v * 0.70710678118654752f));
                if (EPI == 2) v += ((const float*)Rv)[(size_t)rowm * N + c];
                if (EPI == 3) {
                    v += bf2f(((const unsigned short*)Rv)[(size_t)rowm * N + c]);
                    ((float*)outv)[(size_t)rowm * N + c] = v;
                } else {
                    ((unsigned short*)outv)[(size_t)rowm * N + c] = f2bf(v);
                }
            }
        }
    }
}

// ---------------------------------------------------------------------------
// Barrier-free one-wave flash attention with dense edge bias.
// Grid (T/16, B*H/2); block 128 = 2 INDEPENDENT waves (no __syncthreads).
// Wave handles (bh, 16 q-rows). K frags + bias + mask direct from global.
// V reg-transposed into private LDS strip (stride 40, packed b32 writes).
// S^T = K @ Q^T; online softmax; P via per-wave LDS; O^T += V^T @ P^T.
// ---------------------------------------------------------------------------
__global__ __launch_bounds__(128) void attn_mfma(const unsigned short* __restrict__ qkv,
                                                 const float* __restrict__ bias,
                                                 const unsigned char* __restrict__ mask,
                                                 unsigned short* __restrict__ o)
{
    __shared__ unsigned short Vt_s[2][32][40];  // per-wave [d][kv]
    __shared__ unsigned short P_s[2][16][72];   // per-wave [q][kv]

    int tid  = threadIdx.x;
    int lane = tid & 63;
    int w    = tid >> 6;
    int l15  = lane & 15, lg = lane >> 4;
    int bh = blockIdx.y * 2 + w, b = bh >> 3, hh = bh & 7;
    int q0 = blockIdx.x * 16;
    const float scale = 0.17677669529663687f;  // 1/sqrt(32)

    // Q fragment (B-operand): q = l15, d = lg*8..+7
    bf16x8 qf = *(const bf16x8*)(qkv + ((size_t)(q0 + l15) * B_DIM + b) * 768 + hh * 32 + lg * 8);
    const float* bptr = bias + ((size_t)bh * T_DIM + q0 + l15) * T_DIM + lg * 4;

    float m_run = -INFINITY, l_run = 0.0f;
    f32x4 oacc[2] = {};  // lane: q = l15, d = db*16 + lg*4 + r

    for (int k0 = 0; k0 < T_DIM; k0 += 64) {
        // ---- global loads for this tile (registers; no barrier anywhere) ----
        f32x4 bb[4];
        bf16x8 kf[4];
        uint32_t mw[4];
#pragma unroll
        for (int kb = 0; kb < 4; kb++) {
            bb[kb] = *(const f32x4*)(bptr + k0 + kb * 16);
            kf[kb] = *(const bf16x8*)(qkv + ((size_t)(k0 + kb * 16 + l15) * B_DIM + b) * 768
                                      + 256 + hh * 32 + lg * 8);
            mw[kb] = *(const uint32_t*)(mask + (size_t)b * T_DIM + k0 + kb * 16 + lg * 4);
        }
        // ---- V 64x32 -> transposed LDS strip (packed b32 writes) ----
#pragma unroll
        for (int j = 0; j < 8; j++) {
            int p = j * 64 + lane;
            int kv2 = p >> 4, dp = (p & 15) * 2;
            const unsigned short* vp = qkv + ((size_t)(k0 + kv2 * 2) * B_DIM + b) * 768
                                       + 512 + hh * 32 + dp;
            uint32_t v0 = *(const uint32_t*)vp;
            uint32_t v1 = *(const uint32_t*)(vp + 768 * B_DIM);
            *(uint32_t*)&Vt_s[w][dp][kv2 * 2]     = (v0 & 0xffffu) | (v1 << 16);
            *(uint32_t*)&Vt_s[w][dp + 1][kv2 * 2] = (v0 >> 16) | (v1 & 0xffff0000u);
        }

        // ---- S^T = K @ Q^T ----
        float sv[4][4];
        float tmax = -INFINITY;
        __builtin_amdgcn_s_setprio(1);
#pragma unroll
        for (int kb = 0; kb < 4; kb++) {
            f32x4 z = {0.0f, 0.0f, 0.0f, 0.0f};
            f32x4 sc = __builtin_amdgcn_mfma_f32_16x16x32_bf16(kf[kb], qf, z, 0, 0, 0);
#pragma unroll
            for (int r = 0; r < 4; r++) {
                float s = sc[r] * scale + bb[kb][r];
                if ((mw[kb] >> (8 * r)) & 0xff) s = -1e9f;
                sv[kb][r] = s;
                tmax = fmaxf(tmax, s);
            }
        }
        __builtin_amdgcn_s_setprio(0);
        tmax = fmaxf(tmax, __shfl_xor(tmax, 16));
        tmax = fmaxf(tmax, __shfl_xor(tmax, 32));
        float m_new = fmaxf(m_run, tmax);
        float corr = __expf(m_run - m_new);
        m_run = m_new;

        float ls = 0.0f;
#pragma unroll
        for (int kb = 0; kb < 4; kb++) {
            float p0 = __expf(sv[kb][0] - m_new);
            float p1 = __expf(sv[kb][1] - m_new);
            float p2 = __expf(sv[kb][2] - m_new);
            float p3 = __expf(sv[kb][3] - m_new);
            ls += (p0 + p1) + (p2 + p3);
            uint2 pw;
            pw.x = (uint32_t)f2bf(p0) | ((uint32_t)f2bf(p1) << 16);
            pw.y = (uint32_t)f2bf(p2) | ((uint32_t)f2bf(p3) << 16);
            *(uint2*)&P_s[w][l15][kb * 16 + lg * 4] = pw;   // same-wave produce
        }
        ls += __shfl_xor(ls, 16);
        ls += __shfl_xor(ls, 32);
        l_run = l_run * corr + ls;
#pragma unroll
        for (int db = 0; db < 2; db++)
#pragma unroll
            for (int r = 0; r < 4; r++) oacc[db][r] *= corr;

        // ---- O^T += V^T @ P^T ----
        __builtin_amdgcn_s_setprio(1);
#pragma unroll
        for (int h = 0; h < 2; h++) {
            bf16x8 pf = *(const bf16x8*)&P_s[w][l15][h * 32 + lg * 8];
#pragma unroll
            for (int db = 0; db < 2; db++) {
                bf16x8 vf = *(const bf16x8*)&Vt_s[w][db * 16 + l15][h * 32 + lg * 8];
                oacc[db] = __builtin_amdgcn_mfma_f32_16x16x32_bf16(vf, pf, oacc[db], 0, 0, 0);
            }
        }
        __builtin_amdgcn_s_setprio(0);
    }

    // direct store: token = q0+l15, dims d = db*16 + lg*4 + r (4 contiguous)
    float inv = 1.0f / l_run;
#pragma unroll
    for (int db = 0; db < 2; db++) {
        ushort4 ov;
        ov.x = f2bf(oacc[db][0] * inv);
        ov.y = f2bf(oacc[db][1] * inv);
        ov.z = f2bf(oacc[db][2] * inv);
        ov.w = f2bf(oacc[db][3] * inv);
        *(ushort4*)(o + ((size_t)(q0 + l15) * B_DIM + b) * C_DIM + hh * 32 + db * 16 + lg * 4) = ov;
    }
}

// ---------------------------------------------------------------------------
extern "C" void kernel_launch(void* const* d_in, const int* in_sizes, int n_in,
                              void* d_out, int out_size, void* d_ws, size_t ws_size,
                              hipStream_t stream)
{
    const float* x            = (const float*)d_in[0];
    const unsigned char* mask = (const unsigned char*)d_in[1];
    const float* bias         = (const float*)d_in[2];
    const float* ln1g         = (const float*)d_in[3];
    const float* ln1b         = (const float*)d_in[4];
    const float* ln2g         = (const float*)d_in[5];
    const float* ln2b         = (const float*)d_in[6];
    const float* wqkv         = (const float*)d_in[7];
    const float* bqkv         = (const float*)d_in[8];
    const float* wo           = (const float*)d_in[9];
    const float* bo           = (const float*)d_in[10];
    const float* w1           = (const float*)d_in[11];
    const float* b1           = (const float*)d_in[12];
    const float* w2           = (const float*)d_in[13];
    const float* b2           = (const float*)d_in[14];
    float* out = (float*)d_out;
    char* ws   = (char*)d_ws;

    unsigned short* wbf     = (unsigned short*)ws;                      // 1 MB
    unsigned short* wqkv_bf = wbf;
    unsigned short* wo_bf   = wbf + 196608;
    unsigned short* w1_bf   = wbf + 262144;
    unsigned short* w2_bf   = wbf + 393216;
    unsigned short* y_bf    = (unsigned short*)(ws + (1u << 20));       // 4 MB
    unsigned short* qkv_bf  = (unsigned short*)(ws + 5u * (1u << 20));  // 12 MB
    unsigned short* o_bf    = (unsigned short*)(ws + 17u * (1u << 20)); // 4 MB
    unsigned short* x1_bf   = (unsigned short*)(ws + 21u * (1u << 20)); // 4 MB
    unsigned short* h_bf    = (unsigned short*)(ws + 29u * (1u << 20)); // 8 MB

    const int M = T_DIM * B_DIM;  // 8192

    convert_weights<<<2048, 256, 0, stream>>>(wqkv, wo, w1, w2, wbf);
    ln_bf16<<<M / 4, 256, 0, stream>>>(x, ln1g, ln1b, y_bf);
    gemm_mfma<0><<<dim3(768 / 64, M / 128), 256, 0, stream>>>(y_bf, wqkv_bf, bqkv, nullptr, qkv_bf, 768, 256);
    attn_mfma<<<dim3(T_DIM / 16, B_DIM * H_DIM / 2), 128, 0, stream>>>(qkv_bf, bias, mask, o_bf);
    gemm_mfma<2><<<dim3(256 / 64, M / 128), 256, 0, stream>>>(o_bf, wo_bf, bo, x, x1_bf, 256, 256);
    ln_bf16i<<<M / 4, 256, 0, stream>>>(x1_bf, ln2g, ln2b, y_bf);
    gemm_mfma<1><<<dim3(512 / 64, M / 128), 256, 0, stream>>>(y_bf, w1_bf, b1, nullptr, h_bf, 512, 256);
    gemm_mfma<3><<<dim3(256 / 64, M / 128), 256, 0, stream>>>(h_bf, w2_bf, b2, x1_bf, out, 256, 512);
}